// Round 1
// baseline (1836.466 us; speedup 1.0000x reference)
//
#include <hip/hip_runtime.h>
#include <hip/hip_bf16.h>

// Problem constants (fixed by the reference)
#define BB   2
#define SS   2048
#define DD   1024
#define HH   16
#define HDIM 64

// ---------------------------------------------------------------------------
// helpers
// ---------------------------------------------------------------------------
__device__ __forceinline__ float bcast_lane(float v, int lane) {
#if __has_builtin(__builtin_amdgcn_readlane)
  // SGPR broadcast: stays off the DS pipe (vs __shfl -> ds_bpermute)
  return __int_as_float(__builtin_amdgcn_readlane(__float_as_int(v), lane));
#else
  return __shfl(v, lane, 64);
#endif
}

__device__ __forceinline__ float wave_max(float v) {
#pragma unroll
  for (int off = 32; off > 0; off >>= 1) v = fmaxf(v, __shfl_xor(v, off, 64));
  return v;
}

__device__ __forceinline__ float wave_sum(float v) {
#pragma unroll
  for (int off = 32; off > 0; off >>= 1) v += __shfl_xor(v, off, 64);
  return v;
}

// ---------------------------------------------------------------------------
// Kernel 1: per-head projections  ph[b,h,s,e] = sum_d x[b,s,d] * W[h,d,e]
// grid (SS/16, BB*HH, 3), block 64.  blockIdx.z selects q/k/v.
// Lane = e (W loads coalesced); activation reads are wave-uniform -> s_load.
// ---------------------------------------------------------------------------
__global__ __launch_bounds__(64) void proj_kernel(
    const float* __restrict__ q, const float* __restrict__ k,
    const float* __restrict__ v, const float* __restrict__ Wq,
    const float* __restrict__ Wk, const float* __restrict__ Wv,
    float* __restrict__ qh, float* __restrict__ kh, float* __restrict__ vh) {
  const int e     = threadIdx.x;      // 0..63
  const int stile = blockIdx.x;       // 16 rows each
  const int bh    = blockIdx.y;       // 0..31
  const int which = blockIdx.z;       // 0:q 1:k 2:v
  const int b = bh / HH, h = bh % HH;

  const float* x; const float* W; float* dst;
  if (which == 0)      { x = q; W = Wq; dst = qh; }
  else if (which == 1) { x = k; W = Wk; dst = kh; }
  else                 { x = v; W = Wv; dst = vh; }

  const int s0 = stile * 16;
  const float* xb = x + ((size_t)b * SS + s0) * DD;
  const float* Wh = W + (size_t)h * DD * HDIM + e;

  float acc[16];
#pragma unroll
  for (int r = 0; r < 16; ++r) acc[r] = 0.f;

#pragma unroll 4
  for (int d = 0; d < DD; ++d) {
    float w = Wh[(size_t)d * HDIM];
#pragma unroll
    for (int r = 0; r < 16; ++r) acc[r] += xb[(size_t)r * DD + d] * w;
  }

  float* dsth = dst + ((size_t)bh * SS + s0) * HDIM + e;
#pragma unroll
  for (int r = 0; r < 16; ++r) dsth[(size_t)r * HDIM] = acc[r];
}

// ---------------------------------------------------------------------------
// Kernel 2: flash-style causal attention with the reference's pad-zero mask.
// grid (SS/16, BB*HH), block 256 (4 waves; each wave owns 4 query rows).
// Lane roles: scores -> lane = t (K row in registers, q via readlane);
//             PV     -> lane = e (V column loads coalesced, p via readlane).
// ---------------------------------------------------------------------------
__global__ __launch_bounds__(256) void attn_kernel(
    const float* __restrict__ qh, const float* __restrict__ kh,
    const float* __restrict__ vh, const int* __restrict__ mask,
    float* __restrict__ X) {
  const int lane = threadIdx.x & 63;
  const int wid  = threadIdx.x >> 6;
  const int qb   = blockIdx.x;
  const int bh   = blockIdx.y;
  const int b    = bh >> 4;
  const int row0 = qb * 16 + wid * 4;

  const size_t base = (size_t)bh * SS * HDIM;
  const float* Qp = qh + base;
  const float* Kp = kh + base;
  const float* Vp = vh + base;
  const int*   mb = mask + b * SS;

  float qreg[4], o[4], m[4], l[4];
  int mrow[4];
#pragma unroll
  for (int r = 0; r < 4; ++r) {
    qreg[r] = Qp[(size_t)(row0 + r) * HDIM + lane] * 0.125f;  // 1/sqrt(64)
    o[r] = 0.f; m[r] = -1e30f; l[r] = 0.f;
    mrow[r] = mb[row0 + r];
  }

  const int ntiles = ((row0 + 3) >> 6) + 1;  // causal extent of this wave
  float tile[64];                            // K rows, then V columns

  for (int tb = 0; tb < ntiles; ++tb) {
    const int t0 = tb * 64;
    const int t  = t0 + lane;

    // K[t][0..63] into registers (lane = t), via float4 loads
    const float4* krow = (const float4*)(Kp + (size_t)t * HDIM);
#pragma unroll
    for (int j4 = 0; j4 < 16; ++j4) {
      float4 kk = krow[j4];
      tile[4 * j4 + 0] = kk.x; tile[4 * j4 + 1] = kk.y;
      tile[4 * j4 + 2] = kk.z; tile[4 * j4 + 3] = kk.w;
    }
    const int mt = mb[t];

    float p[4];
#pragma unroll
    for (int r = 0; r < 4; ++r) {
      float sc = 0.f;
#pragma unroll
      for (int e = 0; e < 64; ++e) sc += bcast_lane(qreg[r], e) * tile[e];
      // reference order: pad-zero first, causal -1e30 second (causal wins)
      if (mrow[r] || mt) sc = 0.f;
      if (t > row0 + r)  sc = -1e30f;

      float tmax  = wave_max(sc);
      float mnew  = fmaxf(m[r], tmax);
      float alpha = __expf(m[r] - mnew);
      float pl    = __expf(sc - mnew);
      l[r] = l[r] * alpha + wave_sum(pl);
      o[r] *= alpha;
      m[r] = mnew;
      p[r] = pl;
    }

    // V[t0..t0+63][lane] into registers (lane = e), coalesced per t
#pragma unroll
    for (int j = 0; j < 64; ++j)
      tile[j] = Vp[(size_t)(t0 + j) * HDIM + lane];

#pragma unroll
    for (int r = 0; r < 4; ++r) {
#pragma unroll
      for (int tt = 0; tt < 64; ++tt)
        o[r] += bcast_lane(p[r], tt) * tile[tt];
    }
  }

#pragma unroll
  for (int r = 0; r < 4; ++r)
    X[base + (size_t)(row0 + r) * HDIM + lane] = o[r] / l[r];
}

// ---------------------------------------------------------------------------
// Kernel 3: out = view(X) @ Wo.  X stored [B,H,S,hd] contiguous == the
// reference's raw reshape to [B,S,D].  grid (SS/16, BB, DD/64), block 64.
// ---------------------------------------------------------------------------
__global__ __launch_bounds__(64) void oproj_kernel(
    const float* __restrict__ X, const float* __restrict__ Wo,
    float* __restrict__ out) {
  const int j  = blockIdx.z * 64 + threadIdx.x;
  const int b  = blockIdx.y;
  const int s0 = blockIdx.x * 16;

  const float* xb = X + ((size_t)b * SS + s0) * DD;
  const float* Wj = Wo + j;

  float acc[16];
#pragma unroll
  for (int r = 0; r < 16; ++r) acc[r] = 0.f;

#pragma unroll 4
  for (int d = 0; d < DD; ++d) {
    float w = Wj[(size_t)d * DD];
#pragma unroll
    for (int r = 0; r < 16; ++r) acc[r] += xb[(size_t)r * DD + d] * w;
  }

  float* ob = out + ((size_t)b * SS + s0) * DD + j;
#pragma unroll
  for (int r = 0; r < 16; ++r) ob[(size_t)r * DD] = acc[r];
}

// ---------------------------------------------------------------------------
extern "C" void kernel_launch(void* const* d_in, const int* in_sizes, int n_in,
                              void* d_out, int out_size, void* d_ws,
                              size_t ws_size, hipStream_t stream) {
  const float* q    = (const float*)d_in[0];
  const float* k    = (const float*)d_in[1];
  const float* v    = (const float*)d_in[2];
  const float* Wq   = (const float*)d_in[3];
  const float* Wk   = (const float*)d_in[4];
  const float* Wv   = (const float*)d_in[5];
  const float* Wo   = (const float*)d_in[6];
  const int*   mask = (const int*)d_in[7];
  float* out = (float*)d_out;

  // workspace: qh | kh | vh | X   (4 x 16 MB fp32 = 64 MB)
  float* ws = (float*)d_ws;
  const size_t NP = (size_t)BB * HH * SS * HDIM;  // 4M elements
  float* qh = ws;
  float* kh = ws + NP;
  float* vh = ws + 2 * NP;
  float* X  = ws + 3 * NP;

  proj_kernel<<<dim3(SS / 16, BB * HH, 3), 64, 0, stream>>>(
      q, k, v, Wq, Wk, Wv, qh, kh, vh);
  attn_kernel<<<dim3(SS / 16, BB * HH), 256, 0, stream>>>(qh, kh, vh, mask, X);
  oproj_kernel<<<dim3(SS / 16, BB, DD / 64), 64, 0, stream>>>(X, Wo, out);
}

// Round 2
// 333.972 us; speedup vs baseline: 5.4989x; 5.4989x over previous
//
#include <hip/hip_runtime.h>
#include <hip/hip_bf16.h>

#define BB 2
#define SS 2048
#define DD 1024
#define HH 16
#define HD 64

typedef __attribute__((ext_vector_type(8))) short bf16x8;
typedef __attribute__((ext_vector_type(4))) float floatx4;

__device__ __forceinline__ short f2bf(float x) {
  __hip_bfloat16 h = __float2bfloat16(x);
  return __builtin_bit_cast(short, h);
}

// async global->LDS, 16B per lane; LDS dest is wave-uniform base + lane*16
__device__ __forceinline__ void load_lds16(const short* g, short* l) {
  __builtin_amdgcn_global_load_lds(
      (const __attribute__((address_space(1))) unsigned int*)g,
      (__attribute__((address_space(3))) unsigned int*)l, 16, 0, 0);
}

__device__ __forceinline__ float redmax16(float v) {
  v = fmaxf(v, __shfl_xor(v, 1, 64));
  v = fmaxf(v, __shfl_xor(v, 2, 64));
  v = fmaxf(v, __shfl_xor(v, 4, 64));
  v = fmaxf(v, __shfl_xor(v, 8, 64));
  return v;
}
__device__ __forceinline__ float redsum16(float v) {
  v += __shfl_xor(v, 1, 64);
  v += __shfl_xor(v, 2, 64);
  v += __shfl_xor(v, 4, 64);
  v += __shfl_xor(v, 8, 64);
  return v;
}

// ---------------------------------------------------------------------------
// fp32 -> bf16 element-wise for q,k,v. grid (4096,1,3), block 256.
// ---------------------------------------------------------------------------
__global__ __launch_bounds__(256) void conv_in(
    const float* __restrict__ q, const float* __restrict__ k,
    const float* __restrict__ v, short* __restrict__ qo,
    short* __restrict__ ko, short* __restrict__ vo) {
  const float* src = blockIdx.z == 0 ? q : blockIdx.z == 1 ? k : v;
  short* dst       = blockIdx.z == 0 ? qo : blockIdx.z == 1 ? ko : vo;
  size_t i = ((size_t)blockIdx.x * 256 + threadIdx.x) * 4;
  float4 f = *(const float4*)(src + i);
  short4 s;
  s.x = f2bf(f.x); s.y = f2bf(f.y); s.z = f2bf(f.z); s.w = f2bf(f.w);
  *(short4*)(dst + i) = s;
}

// ---------------------------------------------------------------------------
// Wq/Wk/Wv [16][1024][64] fp32 -> WT [16][64][1024] bf16 (transposed, n-major)
// grid (16 dtiles, 16 heads, 3), block 256, tile 64x64.
// ---------------------------------------------------------------------------
__global__ __launch_bounds__(256) void conv_w(
    const float* __restrict__ Wq, const float* __restrict__ Wk,
    const float* __restrict__ Wv, short* __restrict__ qT,
    short* __restrict__ kT, short* __restrict__ vT) {
  __shared__ short sT[64 * 72];
  const float* W = blockIdx.z == 0 ? Wq : blockIdx.z == 1 ? Wk : Wv;
  short* WT      = blockIdx.z == 0 ? qT : blockIdx.z == 1 ? kT : vT;
  const int h = blockIdx.y, d0 = blockIdx.x * 64;
  const int t = threadIdx.x, r = t >> 2, c0 = (t & 3) * 16;
  const float4* src = (const float4*)(W + ((size_t)h * DD + d0 + r) * HD + c0);
  float4 f0 = src[0], f1 = src[1], f2 = src[2], f3 = src[3];
  const float ff[16] = {f0.x, f0.y, f0.z, f0.w, f1.x, f1.y, f1.z, f1.w,
                        f2.x, f2.y, f2.z, f2.w, f3.x, f3.y, f3.z, f3.w};
#pragma unroll
  for (int j = 0; j < 16; ++j) sT[r * 72 + c0 + j] = f2bf(ff[j]);
  __syncthreads();
  // write WT row e = r, d-cols c0..c0+15
  alignas(16) short tmp[16];
#pragma unroll
  for (int j = 0; j < 16; ++j) tmp[j] = sT[(c0 + j) * 72 + r];
  short* dst = WT + ((size_t)h * HD + r) * DD + d0 + c0;
  *(int4*)(dst) = *(const int4*)(tmp);
  *(int4*)(dst + 8) = *(const int4*)(tmp + 8);
}

// ---------------------------------------------------------------------------
// Wo [1024][1024] fp32 -> WoT [n][k] bf16 transposed. grid (16,16), tile 64x64
// ---------------------------------------------------------------------------
__global__ __launch_bounds__(256) void conv_wo(const float* __restrict__ Wo,
                                               short* __restrict__ WoT) {
  __shared__ short sT[64 * 72];
  const int k0 = blockIdx.x * 64, n0 = blockIdx.y * 64;
  const int t = threadIdx.x, r = t >> 2, c0 = (t & 3) * 16;
  const float4* src = (const float4*)(Wo + (size_t)(k0 + r) * DD + n0 + c0);
  float4 f0 = src[0], f1 = src[1], f2 = src[2], f3 = src[3];
  const float ff[16] = {f0.x, f0.y, f0.z, f0.w, f1.x, f1.y, f1.z, f1.w,
                        f2.x, f2.y, f2.z, f2.w, f3.x, f3.y, f3.z, f3.w};
#pragma unroll
  for (int j = 0; j < 16; ++j) sT[r * 72 + c0 + j] = f2bf(ff[j]);
  __syncthreads();
  alignas(16) short tmp[16];
#pragma unroll
  for (int j = 0; j < 16; ++j) tmp[j] = sT[(c0 + j) * 72 + r];
  short* dst = WoT + (size_t)(n0 + r) * DD + k0 + c0;
  *(int4*)(dst) = *(const int4*)(tmp);
  *(int4*)(dst + 8) = *(const int4*)(tmp + 8);
}

// ---------------------------------------------------------------------------
// Projection GEMM: ph = x @ W[h], M=4096 N=64 K=1024, bf16 MFMA.
// BM=256 BN=64 BK=32, 256 threads (4 waves, each 64 rows x 64 cols).
// qh output pre-scaled by 1/8. grid (16, 16 heads, 3).
// ---------------------------------------------------------------------------
__global__ __launch_bounds__(256) void proj(
    const short* __restrict__ xq, const short* __restrict__ xk,
    const short* __restrict__ xv, const short* __restrict__ WqT,
    const short* __restrict__ WkT, const short* __restrict__ WvT,
    short* __restrict__ qh, short* __restrict__ kh, short* __restrict__ vh) {
  __shared__ short sA[256 * 32];
  __shared__ short sB[64 * 32];
  const int which = blockIdx.z;
  const short* X  = which == 0 ? xq : which == 1 ? xk : xv;
  const short* WT = which == 0 ? WqT : which == 1 ? WkT : WvT;
  short* dst      = which == 0 ? qh : which == 1 ? kh : vh;
  const int h = blockIdx.y;
  const int s0 = blockIdx.x * 256;
  const int tid = threadIdx.x, wid = tid >> 6, lane = tid & 63;
  const int quad = lane >> 4, l16 = lane & 15;

  floatx4 acc[4][4] = {};
  for (int k0 = 0; k0 < DD; k0 += 32) {
    __syncthreads();
#pragma unroll
    for (int i = 0; i < 4; ++i) {
      const int c = wid * 4 + i;
      const int ci = c * 64 + lane;
      load_lds16(X + (size_t)(s0 + (ci >> 2)) * DD + k0 + (ci & 3) * 8,
                 &sA[c * 512]);
    }
    {
      const int ci = wid * 64 + lane;
      load_lds16(WT + ((size_t)h * HD + (ci >> 2)) * DD + k0 + (ci & 3) * 8,
                 &sB[wid * 512]);
    }
    __syncthreads();
    bf16x8 af[4], bfr[4];
#pragma unroll
    for (int mi = 0; mi < 4; ++mi)
      af[mi] = *(const bf16x8*)&sA[(wid * 64 + mi * 16 + l16) * 32 + quad * 8];
#pragma unroll
    for (int ni = 0; ni < 4; ++ni)
      bfr[ni] = *(const bf16x8*)&sB[(ni * 16 + l16) * 32 + quad * 8];
#pragma unroll
    for (int mi = 0; mi < 4; ++mi)
#pragma unroll
      for (int ni = 0; ni < 4; ++ni)
        acc[mi][ni] = __builtin_amdgcn_mfma_f32_16x16x32_bf16(
            af[mi], bfr[ni], acc[mi][ni], 0, 0, 0);
  }
  const float scale = (which == 0) ? 0.125f : 1.0f;  // fold 1/sqrt(64) into Q
#pragma unroll
  for (int mi = 0; mi < 4; ++mi)
#pragma unroll
    for (int ni = 0; ni < 4; ++ni)
#pragma unroll
      for (int r2 = 0; r2 < 4; ++r2) {
        const int row = s0 + wid * 64 + mi * 16 + quad * 4 + r2;  // 0..4095
        const int b = row >> 11, s = row & 2047;
        const int col = ni * 16 + l16;
        dst[(((size_t)(b * HH + h)) * SS + s) * HD + col] =
            f2bf(acc[mi][ni][r2] * scale);
      }
}

// ---------------------------------------------------------------------------
// vh [bh][2048][64] bf16 -> vhT [bh][64][2048] bf16. grid (32, 32 bh).
// ---------------------------------------------------------------------------
__global__ __launch_bounds__(256) void vtrans(const short* __restrict__ vh,
                                              short* __restrict__ vhT) {
  __shared__ short sT[64 * 72];
  const int bh = blockIdx.y, s0 = blockIdx.x * 64;
  const int t = threadIdx.x, r = t >> 2, c0 = (t & 3) * 16;
  const short* src = vh + ((size_t)bh * SS + s0 + r) * HD + c0;
  *(int4*)&sT[r * 72 + c0] = *(const int4*)src;
  *(int4*)&sT[r * 72 + c0 + 8] = *(const int4*)(src + 8);
  __syncthreads();
  alignas(16) short tmp[16];
#pragma unroll
  for (int j = 0; j < 16; ++j) tmp[j] = sT[(c0 + j) * 72 + r];
  short* dst = vhT + ((size_t)bh * HD + r) * SS + s0 + c0;
  *(int4*)(dst) = *(const int4*)(tmp);
  *(int4*)(dst + 8) = *(const int4*)(tmp + 8);
}

// ---------------------------------------------------------------------------
// Flash attention, bf16 MFMA. Block = 256 (4 waves), 128 q-rows/block,
// wave = 32 q-rows. t-tiles of 64. grid (16 qb, 32 bh).
// ---------------------------------------------------------------------------
__global__ __launch_bounds__(256) void attn(
    const short* __restrict__ qh, const short* __restrict__ kh,
    const short* __restrict__ vhT, const int* __restrict__ mask,
    short* __restrict__ X) {
  __shared__ short sP[4][32 * 72];  // per-wave P tile, padded stride 72
  const int tid = threadIdx.x, wid = tid >> 6, lane = tid & 63;
  const int quad = lane >> 4, l16 = lane & 15;
  const int qb = gridDim.x - 1 - blockIdx.x;  // heavy (high-qb) blocks first
  const int bh = blockIdx.y, b = bh >> 4;
  const int row0 = qb * 128 + wid * 32;

  const short* Q  = qh + (size_t)bh * SS * HD;
  const short* K  = kh + (size_t)bh * SS * HD;
  const short* Vt = vhT + (size_t)bh * HD * SS;
  const int* mk = mask + b * SS;

  // Q fragments: A-layout, m=lane&15, k=quad*8+j (ks selects k 0..31 / 32..63)
  bf16x8 aq[2][2];
#pragma unroll
  for (int mi = 0; mi < 2; ++mi)
#pragma unroll
    for (int ks = 0; ks < 2; ++ks)
      aq[mi][ks] = *(const bf16x8*)(Q + (size_t)(row0 + mi * 16 + l16) * HD +
                                    ks * 32 + quad * 8);
  int mrow[2][4];
#pragma unroll
  for (int mi = 0; mi < 2; ++mi)
#pragma unroll
    for (int r2 = 0; r2 < 4; ++r2)
      mrow[mi][r2] = mk[row0 + mi * 16 + quad * 4 + r2];

  floatx4 o[2][4] = {};
  float mrun[2][4], lrun[2][4];
#pragma unroll
  for (int mi = 0; mi < 2; ++mi)
#pragma unroll
    for (int r2 = 0; r2 < 4; ++r2) { mrun[mi][r2] = -1e30f; lrun[mi][r2] = 0.f; }

  const int ntiles = ((row0 + 31) >> 6) + 1;
  for (int tb = 0; tb < ntiles; ++tb) {
    const int t0 = tb * 64;
    // ---- S = Q K^T (K rows are B-fragments: n=t, k=e contiguous) ----
    floatx4 s[2][4] = {};
#pragma unroll
    for (int ks = 0; ks < 2; ++ks) {
      bf16x8 bk[4];
#pragma unroll
      for (int ni = 0; ni < 4; ++ni)
        bk[ni] = *(const bf16x8*)(K + (size_t)(t0 + ni * 16 + l16) * HD +
                                  ks * 32 + quad * 8);
#pragma unroll
      for (int mi = 0; mi < 2; ++mi)
#pragma unroll
        for (int ni = 0; ni < 4; ++ni)
          s[mi][ni] = __builtin_amdgcn_mfma_f32_16x16x32_bf16(
              aq[mi][ks], bk[ni], s[mi][ni], 0, 0, 0);
    }
    int mt[4];
#pragma unroll
    for (int ni = 0; ni < 4; ++ni) mt[ni] = mk[t0 + ni * 16 + l16];

    // ---- masking + online softmax (per row-slot) ----
#pragma unroll
    for (int mi = 0; mi < 2; ++mi) {
#pragma unroll
      for (int r2 = 0; r2 < 4; ++r2) {
        const int row = row0 + mi * 16 + quad * 4 + r2;
        const int padr = mrow[mi][r2];
        float sv[4];
#pragma unroll
        for (int ni = 0; ni < 4; ++ni) {
          const int col = t0 + ni * 16 + l16;
          float x = s[mi][ni][r2];
          if (padr | mt[ni]) x = 0.f;      // reference: pad -> 0.0 first
          if (col > row) x = -1e30f;       // then causal -> -1e30
          sv[ni] = x;
        }
        float mx = fmaxf(fmaxf(sv[0], sv[1]), fmaxf(sv[2], sv[3]));
        mx = redmax16(mx);
        const float mnew = fmaxf(mrun[mi][r2], mx);
        const float alpha = __expf(mrun[mi][r2] - mnew);
        float ps = 0.f;
#pragma unroll
        for (int ni = 0; ni < 4; ++ni) {
          const float p = __expf(sv[ni] - mnew);
          ps += p;
          sP[wid][(mi * 16 + quad * 4 + r2) * 72 + ni * 16 + l16] = f2bf(p);
        }
        ps = redsum16(ps);
        lrun[mi][r2] = lrun[mi][r2] * alpha + ps;
        mrun[mi][r2] = mnew;
#pragma unroll
        for (int ei = 0; ei < 4; ++ei) o[mi][ei][r2] *= alpha;
      }
    }
    // ---- O += P V  (P via LDS round-trip into A-layout; Vt B-frags) ----
#pragma unroll
    for (int ks = 0; ks < 2; ++ks) {
      bf16x8 ap[2], bv[4];
#pragma unroll
      for (int mi = 0; mi < 2; ++mi)
        ap[mi] = *(const bf16x8*)&sP[wid][(mi * 16 + l16) * 72 + ks * 32 +
                                          quad * 8];
#pragma unroll
      for (int ei = 0; ei < 4; ++ei)
        bv[ei] = *(const bf16x8*)(Vt + (size_t)(ei * 16 + l16) * SS + t0 +
                                  ks * 32 + quad * 8);
#pragma unroll
      for (int mi = 0; mi < 2; ++mi)
#pragma unroll
        for (int ei = 0; ei < 4; ++ei)
          o[mi][ei] = __builtin_amdgcn_mfma_f32_16x16x32_bf16(
              ap[mi], bv[ei], o[mi][ei], 0, 0, 0);
    }
  }
  // ---- epilogue: O /= l, store bf16 (raw [bh][s][e] view == reference) ----
#pragma unroll
  for (int mi = 0; mi < 2; ++mi)
#pragma unroll
    for (int r2 = 0; r2 < 4; ++r2) {
      const float inv = 1.0f / lrun[mi][r2];
      const int row = row0 + mi * 16 + quad * 4 + r2;
#pragma unroll
      for (int ei = 0; ei < 4; ++ei)
        X[((size_t)bh * SS + row) * HD + ei * 16 + l16] =
            f2bf(o[mi][ei][r2] * inv);
    }
}

// ---------------------------------------------------------------------------
// out = X[4096,1024] @ Wo, via WoT[n][k]. BM=BN=128 BK=32, 256 threads.
// grid (32, 8). fp32 output.
// ---------------------------------------------------------------------------
__global__ __launch_bounds__(256) void oproj(const short* __restrict__ X,
                                             const short* __restrict__ WoT,
                                             float* __restrict__ out) {
  __shared__ short sA[128 * 32];
  __shared__ short sB[128 * 32];
  const int m0 = blockIdx.x * 128, n0 = blockIdx.y * 128;
  const int tid = threadIdx.x, wid = tid >> 6, lane = tid & 63;
  const int quad = lane >> 4, l16 = lane & 15;
  const int wr = wid >> 1, wc = wid & 1;

  floatx4 acc[4][4] = {};
  for (int k0 = 0; k0 < DD; k0 += 32) {
    __syncthreads();
#pragma unroll
    for (int i = 0; i < 2; ++i) {
      const int c = wid * 2 + i;
      const int ci = c * 64 + lane;
      load_lds16(X + (size_t)(m0 + (ci >> 2)) * DD + k0 + (ci & 3) * 8,
                 &sA[c * 512]);
      load_lds16(WoT + (size_t)(n0 + (ci >> 2)) * DD + k0 + (ci & 3) * 8,
                 &sB[c * 512]);
    }
    __syncthreads();
    bf16x8 af[4], bfr[4];
#pragma unroll
    for (int mi = 0; mi < 4; ++mi)
      af[mi] = *(const bf16x8*)&sA[(wr * 64 + mi * 16 + l16) * 32 + quad * 8];
#pragma unroll
    for (int ni = 0; ni < 4; ++ni)
      bfr[ni] = *(const bf16x8*)&sB[(wc * 64 + ni * 16 + l16) * 32 + quad * 8];
#pragma unroll
    for (int mi = 0; mi < 4; ++mi)
#pragma unroll
      for (int ni = 0; ni < 4; ++ni)
        acc[mi][ni] = __builtin_amdgcn_mfma_f32_16x16x32_bf16(
            af[mi], bfr[ni], acc[mi][ni], 0, 0, 0);
  }
#pragma unroll
  for (int mi = 0; mi < 4; ++mi)
#pragma unroll
    for (int ni = 0; ni < 4; ++ni)
#pragma unroll
      for (int r2 = 0; r2 < 4; ++r2)
        out[(size_t)(m0 + wr * 64 + mi * 16 + quad * 4 + r2) * DD + n0 +
            wc * 64 + ni * 16 + l16] = acc[mi][ni][r2];
}

// ---------------------------------------------------------------------------
extern "C" void kernel_launch(void* const* d_in, const int* in_sizes, int n_in,
                              void* d_out, int out_size, void* d_ws,
                              size_t ws_size, hipStream_t stream) {
  const float* q  = (const float*)d_in[0];
  const float* k  = (const float*)d_in[1];
  const float* v  = (const float*)d_in[2];
  const float* Wq = (const float*)d_in[3];
  const float* Wk = (const float*)d_in[4];
  const float* Wv = (const float*)d_in[5];
  const float* Wo = (const float*)d_in[6];
  const int* mask = (const int*)d_in[7];
  float* out = (float*)d_out;

  // workspace layout (shorts); X aliases qb, vhT aliases kb (dead by then)
  short* ws = (short*)d_ws;
  const size_t NIN = (size_t)BB * SS * DD;       // 4,194,304
  const size_t NWH = (size_t)HH * HD * DD;       // 1,048,576
  const size_t NPH = (size_t)BB * HH * SS * HD;  // 4,194,304
  short* qb  = ws;                // also X
  short* kb  = ws + NIN;          // also vhT
  short* vb  = ws + 2 * NIN;
  short* WqT = ws + 3 * NIN;
  short* WkT = WqT + NWH;
  short* WvT = WkT + NWH;
  short* WoT = WvT + NWH;
  short* qhp = WoT + (size_t)DD * DD;
  short* khp = qhp + NPH;
  short* vhp = khp + NPH;
  short* Xp  = qb;
  short* vhT = kb;

  conv_in<<<dim3(4096, 1, 3), 256, 0, stream>>>(q, k, v, qb, kb, vb);
  conv_w<<<dim3(16, 16, 3), 256, 0, stream>>>(Wq, Wk, Wv, WqT, WkT, WvT);
  conv_wo<<<dim3(16, 16), 256, 0, stream>>>(Wo, WoT);
  proj<<<dim3(16, 16, 3), 256, 0, stream>>>(qb, kb, vb, WqT, WkT, WvT, qhp,
                                            khp, vhp);
  vtrans<<<dim3(32, 32), 256, 0, stream>>>(vhp, vhT);
  attn<<<dim3(16, 32), 256, 0, stream>>>(qhp, khp, vhT, mask, Xp);
  oproj<<<dim3(32, 8), 256, 0, stream>>>(Xp, WoT, out);
}